// Round 4
// baseline (452.837 us; speedup 1.0000x reference)
//
#include <hip/hip_runtime.h>

// Problem constants (GraphNet_41944650613153)
#define NN    156            // real nodes per graph
#define NP    160            // padded nodes (MFMA tiles of 16)
#define CN    128            // channels
#define K0    301            // layer-0 input channels
#define KP0   320            // padded K for layer 0
#define BATCH 1024
#define NG    2              // graphs per block

#define W0_OFF 0
#define W1_OFF (128 * KP0)
#define W2_OFF (128 * KP0 + 128 * 128)

typedef __attribute__((ext_vector_type(8))) short bf16x8;  // 8 bf16 (4 VGPRs)
typedef __attribute__((ext_vector_type(4))) float f32x4;   // 4 fp32

// Pre-transposed hi/lo-split weights Wt[n][k]=W[k][n] (zero-padded k, BN scale
// folded into W0/W1 columns) and the dense normalized adjacency Adj[dst][src]
// (shared by all graphs, L2-resident).
__device__ __align__(16) ushort g_WtH[128 * (KP0 + 128 + 128)];
__device__ __align__(16) ushort g_WtL[128 * (KP0 + 128 + 128)];
__device__ __align__(16) ushort g_AdjH[NP * NP];
__device__ __align__(16) ushort g_AdjL[NP * NP];

__device__ __forceinline__ ushort bf16_rne(float f) {
    return __builtin_bit_cast(ushort, (__bf16)f);        // HW RNE convert
}
__device__ __forceinline__ float bf16_f(ushort h) {
    return __builtin_bit_cast(float, (uint32_t)h << 16);
}
__device__ __forceinline__ ushort bf16_lo(float f, ushort h) {
    return (ushort)(__builtin_bit_cast(uint32_t, f - bf16_f(h)) >> 16);
}

// Barrier with LDS-only drain: keeps global (vmem) prefetches in flight.
// Safe here: all cross-wave communication in fused_all goes through LDS.
__device__ __forceinline__ void barrier_lgkm() {
    asm volatile("s_waitcnt lgkmcnt(0)\n\ts_barrier" ::: "memory");
}

// ---------------------------------------------------------------------------
// prep (block 0): dense normalized adjacency with self-loops and duplicate-
// edge multiplicity. Adj[dst][src] = m * dinv[src] * dinv[dst]; pads = 0.
// wt (blocks 1..288): weight transpose + hi/lo split, BN scale folded in.
// ---------------------------------------------------------------------------
__global__ __launch_bounds__(256) void prep_wt(const int* __restrict__ ei, int E,
        const float* __restrict__ W0, const float* __restrict__ W1,
        const float* __restrict__ W2, const float* __restrict__ bw0,
        const float* __restrict__ bw1) {
    __shared__ float adjf[NP * NP];      // 102,400 B (block 0 only)
    __shared__ int   cnt[NP];
    __shared__ float dinv_s[NP];
    const int t = threadIdx.x;
    if (blockIdx.x == 0) {
        for (int i = t; i < NP * NP; i += 256) adjf[i] = 0.f;
        for (int n = t; n < NP; n += 256) cnt[n] = (n < NN) ? 1 : 0;   // self loop
        __syncthreads();
        for (int e = t; e < E; e += 256) atomicAdd(&cnt[ei[E + e]], 1);
        __syncthreads();
        for (int n = t; n < NP; n += 256)
            dinv_s[n] = (cnt[n] > 0) ? rsqrtf((float)cnt[n]) : 0.f;
        __syncthreads();
        for (int e = t; e < E; e += 256) {
            const int r = ei[e], c = ei[E + e];
            atomicAdd(&adjf[c * NP + r], dinv_s[r] * dinv_s[c]);
        }
        for (int n = t; n < NN; n += 256)
            atomicAdd(&adjf[n * NP + n], dinv_s[n] * dinv_s[n]);
        __syncthreads();
        for (int i = t; i < NP * NP; i += 256) {
            const float v = adjf[i];
            const ushort h = bf16_rne(v);
            g_AdjH[i] = h;
            g_AdjL[i] = bf16_lo(v, h);
        }
    } else {
        const int id = (blockIdx.x - 1) * 256 + t;   // exact: 288*256
        const float* W; int K, KP, woff, local;
        if (id < 128 * KP0)              { W = W0; K = K0;  KP = KP0; woff = W0_OFF; local = id; }
        else if (id < 128 * (KP0 + 128)) { W = W1; K = 128; KP = 128; woff = W1_OFF; local = id - 128 * KP0; }
        else                             { W = W2; K = 128; KP = 128; woff = W2_OFF; local = id - 128 * (KP0 + 128); }
        const int n = local & 127, k = local >> 7;
        const float inv = rsqrtf(1.f + 1e-5f);
        float s = 1.f;                                   // BN scale folded into W
        if (woff == W0_OFF) s = bw0[n] * inv;
        else if (woff == W1_OFF) s = bw1[n] * inv;
        const float f = (k < K) ? W[(size_t)k * CN + n] * s : 0.f;
        const ushort h = bf16_rne(f);
        g_WtH[woff + n * KP + k] = h;
        g_WtL[woff + n * KP + k] = bf16_lo(f, h);
    }
}

// ---------------------------------------------------------------------------
// Fully fused 3-layer GCN, TWO graphs per block, 8 waves, 1 block/CU
// (2 waves/SIMD — same as R3, but every phase serves 2 graphs: per-graph
// barrier count halves, W/Adj fragments feed 2x MFMAs, 2 independent
// accumulator chains fill latency bubbles).
//
// LDS (163,840 B = full CU pool): per graph g: hi plane pH[g] (40,960) +
// lo plane pL[g] (40,960), roles alternating:
//   As (L0 x staging, dbuf): [buf 2][row 160][koct^(row&7) 8][8 bf16] (2x20,480)
//   tT (t transposed)      : [sseg 20][ch 128][8 bf16]
//   h  (activations)       : [cseg 16][row 160][8 bf16]
// Staging layout XOR-swizzles koct by row&7: write AND read conflict-free
// (R3's staging writes were the 8.2M bank-conflict source).
//
// Wave partition (8 waves, per-wave MFMA count identical to R3):
//   GEMM: wave owns rows [wr,wr+80) x chans [wc,wc+32), both graphs:
//     acc[2][5][2]; W frags single-buffered (L0) / dbuf (L1,L2).
//   AGG : wave owns chans [ac,ac+32) x dst [ad,ad+80), both graphs:
//     og[2][2][5]; Adj ring-4 register prefetch shared by both graphs.
//   AGG uses 3 split products (lo*lo dropped).
// ---------------------------------------------------------------------------
__global__ __launch_bounds__(512, 2) void fused_all(
        const float* __restrict__ x,
        const float* __restrict__ cb0, const float* __restrict__ bw0, const float* __restrict__ bb0,
        const float* __restrict__ cb1, const float* __restrict__ bw1, const float* __restrict__ bb1,
        const float* __restrict__ cb2, float* __restrict__ out) {
    __shared__ __align__(16) uint8_t smem[163840];

    const int t = threadIdx.x;
    const int lane = t & 63, wave = t >> 6;
    const int quad = lane >> 4, l15 = lane & 15;
    const int wr = (wave >> 2) * 80;      // GEMM row base (src nodes)
    const int wc = (wave & 3) * 32;       // GEMM chan base (quarter)
    const int ac = (wave & 3) * 32;       // AGG chan base
    const int ad = (wave >> 2) * 80;      // AGG dst base

    uint8_t* const pH[NG] = { smem,         smem + 81920 };
    uint8_t* const pL[NG] = { smem + 40960, smem + 122880 };

    size_t arow0[NG];
    arow0[0] = (size_t)(blockIdx.x * 2) * NN;
    arow0[1] = arow0[0] + NN;

    f32x4 acc[NG][5][2];   // GEMM: per graph 80 rows x 32 chans
    f32x4 og[NG][2][5];    // AGG : per graph 32 chans x 80 dst

    // ---- layer-0 staging: x fp32 -> split planes, BK=64 tiles ----
    const int r0s = t >> 4;      // base row 0..31
    const int c4  = t & 15;      // 4-float group within 64-wide k tile
    float sv[NG][5][4];

    auto stage_load = [&](int kt) {
        const int kk = kt * 64 + c4 * 4;
#pragma unroll
        for (int g = 0; g < NG; g++)
#pragma unroll
            for (int s = 0; s < 5; s++) {
                const int r  = r0s + s * 32;
                const int rc = (r < NN) ? r : (NN - 1);      // clamp pad rows
                const float* xp = x + (arow0[g] + rc) * (size_t)K0;
#pragma unroll
                for (int e = 0; e < 4; e++)
                    sv[g][s][e] = (kk + e < K0) ? xp[kk + e] : 0.f;
            }
    };
    auto stage_write = [&](int buf) {
#pragma unroll
        for (int g = 0; g < NG; g++)
#pragma unroll
            for (int s = 0; s < 5; s++) {
                const int r = r0s + s * 32;
                const int koct = (c4 >> 1) ^ (r & 7);        // XOR bank swizzle
                const int off = buf * 20480 + (r * 8 + koct) * 16 + (c4 & 1) * 8;
                ushort4 hs, ls;
#pragma unroll
                for (int e = 0; e < 4; e++) {
                    const float v = sv[g][s][e];
                    const ushort h = bf16_rne(v);
                    (&hs.x)[e] = h;
                    (&ls.x)[e] = bf16_lo(v, h);
                }
                *(ushort4*)(pH[g] + off) = hs;
                *(ushort4*)(pL[g] + off) = ls;
            }
    };

    // ---- L0 W fragments: [ksub][j], single-buffered per kt ----
    bf16x8 wH[2][2], wL[2][2];
    auto loadW0 = [&](int kt) {
#pragma unroll
        for (int ks = 0; ks < 2; ks++)
#pragma unroll
            for (int j = 0; j < 2; j++) {
                const int wi = W0_OFF + (wc + j * 16 + l15) * KP0 + kt * 64 + ks * 32 + quad * 8;
                wH[ks][j] = *(const bf16x8*)&g_WtH[wi];
                wL[ks][j] = *(const bf16x8*)&g_WtL[wi];
            }
    };
    auto gemm_l0 = [&](int buf) {
#pragma unroll
        for (int ks = 0; ks < 2; ks++)
#pragma unroll
            for (int g = 0; g < NG; g++)
#pragma unroll
            for (int i = 0; i < 5; i++) {
                const int row = wr + i * 16 + l15;
                const int off = buf * 20480 + (row * 8 + ((ks * 4 + quad) ^ (row & 7))) * 16;
                const bf16x8 aH = *(const bf16x8*)(pH[g] + off);
                const bf16x8 aL = *(const bf16x8*)(pL[g] + off);
#pragma unroll
                for (int j = 0; j < 2; j++) {
                    acc[g][i][j] = __builtin_amdgcn_mfma_f32_16x16x32_bf16(aH, wH[ks][j], acc[g][i][j], 0, 0, 0);
                    acc[g][i][j] = __builtin_amdgcn_mfma_f32_16x16x32_bf16(aH, wL[ks][j], acc[g][i][j], 0, 0, 0);
                    acc[g][i][j] = __builtin_amdgcn_mfma_f32_16x16x32_bf16(aL, wH[ks][j], acc[g][i][j], 0, 0, 0);
                }
            }
    };

    // ---- L1/L2 W fragments: [buf][j], double-buffered across kt ----
    bf16x8 wbH[2][2], wbL[2][2];
    auto loadWh = [&](int woff, int kt, int sl) {
#pragma unroll
        for (int j = 0; j < 2; j++) {
            const int wi = woff + (wc + j * 16 + l15) * CN + kt * 32 + quad * 8;
            wbH[sl][j] = *(const bf16x8*)&g_WtH[wi];
            wbL[sl][j] = *(const bf16x8*)&g_WtL[wi];
        }
    };
    auto gemm_h = [&]() {   // caller issued loadWh(woff, 0, 0) before barrier
#pragma unroll
        for (int g = 0; g < NG; g++)
#pragma unroll
            for (int i = 0; i < 5; i++)
#pragma unroll
                for (int j = 0; j < 2; j++) acc[g][i][j] = (f32x4){0.f, 0.f, 0.f, 0.f};
#pragma unroll
        for (int kt = 0; kt < 4; kt++) {
#pragma unroll
            for (int g = 0; g < NG; g++)
#pragma unroll
            for (int i = 0; i < 5; i++) {
                const int off = ((kt * 4 + quad) * NP + wr + i * 16 + l15) << 4;
                const bf16x8 aH = *(const bf16x8*)(pH[g] + off);
                const bf16x8 aL = *(const bf16x8*)(pL[g] + off);
#pragma unroll
                for (int j = 0; j < 2; j++) {
                    acc[g][i][j] = __builtin_amdgcn_mfma_f32_16x16x32_bf16(aH, wbH[kt & 1][j], acc[g][i][j], 0, 0, 0);
                    acc[g][i][j] = __builtin_amdgcn_mfma_f32_16x16x32_bf16(aH, wbL[kt & 1][j], acc[g][i][j], 0, 0, 0);
                    acc[g][i][j] = __builtin_amdgcn_mfma_f32_16x16x32_bf16(aL, wbH[kt & 1][j], acc[g][i][j], 0, 0, 0);
                }
            }
        }
    };
    // W prefetch for next kt, issued between the A-reads and the barrier
    // (kept separate so acc MFMAs above see stable wb regs)
    auto gemm_h_full = [&](int woff) {
#pragma unroll
        for (int g = 0; g < NG; g++)
#pragma unroll
            for (int i = 0; i < 5; i++)
#pragma unroll
                for (int j = 0; j < 2; j++) acc[g][i][j] = (f32x4){0.f, 0.f, 0.f, 0.f};
#pragma unroll
        for (int kt = 0; kt < 4; kt++) {
            if (kt < 3) loadWh(woff, kt + 1, (kt + 1) & 1);
#pragma unroll
            for (int g = 0; g < NG; g++)
#pragma unroll
            for (int i = 0; i < 5; i++) {
                const int off = ((kt * 4 + quad) * NP + wr + i * 16 + l15) << 4;
                const bf16x8 aH = *(const bf16x8*)(pH[g] + off);
                const bf16x8 aL = *(const bf16x8*)(pL[g] + off);
#pragma unroll
                for (int j = 0; j < 2; j++) {
                    acc[g][i][j] = __builtin_amdgcn_mfma_f32_16x16x32_bf16(aH, wbH[kt & 1][j], acc[g][i][j], 0, 0, 0);
                    acc[g][i][j] = __builtin_amdgcn_mfma_f32_16x16x32_bf16(aH, wbL[kt & 1][j], acc[g][i][j], 0, 0, 0);
                    acc[g][i][j] = __builtin_amdgcn_mfma_f32_16x16x32_bf16(aL, wbH[kt & 1][j], acc[g][i][j], 0, 0, 0);
                }
            }
        }
    };
    (void)gemm_h;

    // t (C/D frag: col=ch=l15, row=src=quad*4+rg) -> tT planes [sseg][ch][8]
    auto write_tT = [&]() {
#pragma unroll
        for (int g = 0; g < NG; g++)
#pragma unroll
        for (int i = 0; i < 5; i++)
#pragma unroll
            for (int j = 0; j < 2; j++) {
                const int ch = wc + j * 16 + l15;
                const int s0 = wr + i * 16 + quad * 4;
                const int off = (((s0 >> 3) * CN + ch) << 4) + (s0 & 7) * 2;
                ushort4 hs, ls;
#pragma unroll
                for (int rg = 0; rg < 4; rg++) {
                    const float v = acc[g][i][j][rg];
                    const ushort h = bf16_rne(v);
                    (&hs.x)[rg] = h;
                    (&ls.x)[rg] = bf16_lo(v, h);
                }
                *(ushort4*)(pH[g] + off) = hs;
                *(ushort4*)(pL[g] + off) = ls;
            }
    };

    // ---- Adj fragments: ring-4 register prefetch, shared by both graphs ----
    bf16x8 gjH[4], gjL[4];
    auto adj_pf = [&](int step) {               // step is unroll-constant
        const int k2 = step / 5, nj = step % 5;
        const int ai = (ad + nj * 16 + l15) * NP + k2 * 32 + quad * 8;
        gjH[step & 3] = *(const bf16x8*)&g_AdjH[ai];
        gjL[step & 3] = *(const bf16x8*)&g_AdjL[ai];
    };

    // og[ch][dst] = sum_src tT[ch][src] * Adj[dst][src]  (3-product split)
    auto do_agg = [&]() {
#pragma unroll
        for (int g = 0; g < NG; g++)
#pragma unroll
            for (int mi = 0; mi < 2; mi++)
#pragma unroll
                for (int nj = 0; nj < 5; nj++) og[g][mi][nj] = (f32x4){0.f, 0.f, 0.f, 0.f};
#pragma unroll
        for (int k2 = 0; k2 < 5; k2++) {
            bf16x8 taH[NG][2], taL[NG][2];
#pragma unroll
            for (int g = 0; g < NG; g++)
#pragma unroll
                for (int mi = 0; mi < 2; mi++) {
                    const int off = ((k2 * 4 + quad) * CN + ac + mi * 16 + l15) << 4;
                    taH[g][mi] = *(const bf16x8*)(pH[g] + off);
                    taL[g][mi] = *(const bf16x8*)(pL[g] + off);
                }
#pragma unroll
            for (int nj = 0; nj < 5; nj++) {
                const int step = k2 * 5 + nj, slot = step & 3;
#pragma unroll
                for (int g = 0; g < NG; g++)
#pragma unroll
                for (int mi = 0; mi < 2; mi++) {
                    og[g][mi][nj] = __builtin_amdgcn_mfma_f32_16x16x32_bf16(taH[g][mi], gjH[slot], og[g][mi][nj], 0, 0, 0);
                    og[g][mi][nj] = __builtin_amdgcn_mfma_f32_16x16x32_bf16(taH[g][mi], gjL[slot], og[g][mi][nj], 0, 0, 0);
                    og[g][mi][nj] = __builtin_amdgcn_mfma_f32_16x16x32_bf16(taL[g][mi], gjH[slot], og[g][mi][nj], 0, 0, 0);
                }
                if (step + 4 < 25) adj_pf(step + 4);   // refill slot for step+4
            }
        }
    };

    // og (frag: col=node=l15, row=ch=quad*4+rg) -> relu(og + (cb*s+bb)) -> h
    auto write_h = [&](const float* cb, const float* bw, const float* bb) {
        const float inv = rsqrtf(1.f + 1e-5f);
#pragma unroll
        for (int mi = 0; mi < 2; mi++) {
            const int c0 = ac + mi * 16 + quad * 4;
            const float4 cbv = *(const float4*)&cb[c0];
            const float4 bwv = *(const float4*)&bw[c0];
            const float4 bbv = *(const float4*)&bb[c0];
            float cbf[4];
#pragma unroll
            for (int rg = 0; rg < 4; rg++)
                cbf[rg] = fmaf((&cbv.x)[rg], (&bwv.x)[rg] * inv, (&bbv.x)[rg]);
#pragma unroll
            for (int g = 0; g < NG; g++)
#pragma unroll
            for (int nj = 0; nj < 5; nj++) {
                const int node = ad + nj * 16 + l15;
                const int off = (((c0 >> 3) * NP + node) << 4) + (c0 & 7) * 2;
                ushort4 hs, ls;
#pragma unroll
                for (int rg = 0; rg < 4; rg++) {
                    const float v = fmaxf(og[g][mi][nj][rg] + cbf[rg], 0.f);
                    const ushort h = bf16_rne(v);
                    (&hs.x)[rg] = h;
                    (&ls.x)[rg] = bf16_lo(v, h);
                }
                *(ushort4*)(pH[g] + off) = hs;
                *(ushort4*)(pL[g] + off) = ls;
            }
        }
    };

    auto write_out = [&](const float* cb) {
#pragma unroll
        for (int mi = 0; mi < 2; mi++) {
            const int c0 = ac + mi * 16 + quad * 4;
            const float4 cbv = *(const float4*)&cb[c0];
#pragma unroll
            for (int g = 0; g < NG; g++)
#pragma unroll
            for (int nj = 0; nj < 5; nj++) {
                const int node = ad + nj * 16 + l15;
                if (node < NN) {
                    float4 o;
#pragma unroll
                    for (int rg = 0; rg < 4; rg++)
                        (&o.x)[rg] = og[g][mi][nj][rg] + (&cbv.x)[rg];
                    *(float4*)&out[(arow0[g] + node) * CN + c0] = o;
                }
            }
        }
    };

    // =================== layer 0 (BK=64, 5 iterations) ===================
#pragma unroll
    for (int g = 0; g < NG; g++)
#pragma unroll
        for (int i = 0; i < 5; i++)
#pragma unroll
            for (int j = 0; j < 2; j++) acc[g][i][j] = (f32x4){0.f, 0.f, 0.f, 0.f};
    stage_load(0);
    stage_write(0);
    loadW0(0);
    barrier_lgkm();
#pragma unroll
    for (int kt = 0; kt < 5; kt++) {       // A dbuf; W reloaded after last use
        if (kt < 4) stage_load(kt + 1);
        gemm_l0(kt & 1);
        if (kt < 4) { loadW0(kt + 1); stage_write((kt + 1) & 1); }
        barrier_lgkm();
    }
    write_tT();
    adj_pf(0); adj_pf(1); adj_pf(2); adj_pf(3);   // in flight across barrier
    barrier_lgkm();
    do_agg();
    barrier_lgkm();
    write_h(cb0, bw0, bb0);
    loadWh(W1_OFF, 0, 0);                         // in flight across barrier
    barrier_lgkm();
    // =================== layer 1 ===================
    gemm_h_full(W1_OFF);
    barrier_lgkm();
    write_tT();
    adj_pf(0); adj_pf(1); adj_pf(2); adj_pf(3);
    barrier_lgkm();
    do_agg();
    barrier_lgkm();
    write_h(cb1, bw1, bb1);
    loadWh(W2_OFF, 0, 0);
    barrier_lgkm();
    // =================== layer 2 ===================
    gemm_h_full(W2_OFF);
    barrier_lgkm();
    write_tT();
    adj_pf(0); adj_pf(1); adj_pf(2); adj_pf(3);
    barrier_lgkm();
    do_agg();
    write_out(cb2);
}

// ---------------------------------------------------------------------------
// Orchestration: prep_wt (Adj + scaled weight planes) + one fused kernel.
// ---------------------------------------------------------------------------
extern "C" void kernel_launch(void* const* d_in, const int* in_sizes, int n_in,
                              void* d_out, int out_size, void* d_ws, size_t ws_size,
                              hipStream_t stream) {
    const float* x    = (const float*)d_in[0];
    const int*   ei   = (const int*)  d_in[1];
    const float* W0   = (const float*)d_in[2];
    const float* b0   = (const float*)d_in[3];
    const float* bnw0 = (const float*)d_in[4];
    const float* bnb0 = (const float*)d_in[5];
    const float* W1   = (const float*)d_in[6];
    const float* b1   = (const float*)d_in[7];
    const float* bnw1 = (const float*)d_in[8];
    const float* bnb1 = (const float*)d_in[9];
    const float* W2   = (const float*)d_in[10];
    const float* b2   = (const float*)d_in[11];
    float* out = (float*)d_out;

    const int E = in_sizes[1] / 2;

    prep_wt<<<289, 256, 0, stream>>>(ei, E, W0, W1, W2, bnw0, bnw1);
    fused_all<<<BATCH / NG, 512, 0, stream>>>(x, b0, bnw0, bnb0,
                                              b1, bnw1, bnb1, b2, out);
}